// Round 2
// baseline (1253.447 us; speedup 1.0000x reference)
//
#include <hip/hip_runtime.h>
#include <stdint.h>

#define NTOK 65536
#define KDIM 1280

typedef __attribute__((ext_vector_type(8))) short short8;
typedef __attribute__((ext_vector_type(4))) float floatx4;

__device__ __forceinline__ unsigned short f2bf(float f) {
  union { float f; unsigned int u; } v; v.f = f;
  unsigned int r = v.u + 0x7FFFu + ((v.u >> 16) & 1u);  // RNE
  return (unsigned short)(r >> 16);
}
__device__ __forceinline__ float bf2f(unsigned int u16) {
  union { unsigned int u; float f; } v; v.u = u16 << 16; return v.f;
}

// async global->LDS, 16B per lane; lds base must be wave-uniform (HW adds lane*16)
#define GLDS16(gp, lp) \
  __builtin_amdgcn_global_load_lds((const __attribute__((address_space(1))) void*)(gp), \
                                   (__attribute__((address_space(3))) void*)(lp), 16, 0, 0)

// ---------------- prep kernels ----------------

__global__ __launch_bounds__(256) void cast_x_kernel(const float4* __restrict__ x,
                                                     uint2* __restrict__ xb) {
  size_t i = (size_t)blockIdx.x * 256 + threadIdx.x;
  float4 v = x[i];
  uint2 o;
  o.x = (unsigned)f2bf(v.x) | ((unsigned)f2bf(v.y) << 16);
  o.y = (unsigned)f2bf(v.z) | ((unsigned)f2bf(v.w) << 16);
  xb[i] = o;
}

// W1 [E][1280][256] f32 -> W1t [n=e*256+h][k=0..1279] bf16  (B^T layout)
__global__ __launch_bounds__(256) void pack_w1_kernel(const float* __restrict__ W1,
                                                      unsigned short* __restrict__ W1t) {
  int t = blockIdx.x * 256 + threadIdx.x;
  if (t >= 2048 * 160) return;
  int n = t / 160, kg = t - n * 160;
  int e = n >> 8, h = n & 255;
  int k = kg * 8;
  const float* src = W1 + ((size_t)e * 1280 + k) * 256 + h;
  uint4 o;
  o.x = (unsigned)f2bf(src[0])        | ((unsigned)f2bf(src[256])  << 16);
  o.y = (unsigned)f2bf(src[2 * 256])  | ((unsigned)f2bf(src[3 * 256]) << 16);
  o.z = (unsigned)f2bf(src[4 * 256])  | ((unsigned)f2bf(src[5 * 256]) << 16);
  o.w = (unsigned)f2bf(src[6 * 256])  | ((unsigned)f2bf(src[7 * 256]) << 16);
  *(uint4*)(W1t + (size_t)n * 1280 + k) = o;
}

// W2 [E][256][128] f32 -> W2t [e][n=0..127][k=0..255] bf16
__global__ __launch_bounds__(256) void pack_w2_kernel(const float* __restrict__ W2,
                                                      unsigned short* __restrict__ W2t) {
  int t = blockIdx.x * 256 + threadIdx.x;
  if (t >= 1024 * 32) return;
  int ng = t >> 5, kg = t & 31;        // ng = e*128+n
  int e = ng >> 7, n = ng & 127;
  int k = kg * 8;
  const float* src = W2 + (size_t)e * 32768 + (size_t)k * 128 + n;
  uint4 o;
  o.x = (unsigned)f2bf(src[0])        | ((unsigned)f2bf(src[128])  << 16);
  o.y = (unsigned)f2bf(src[2 * 128])  | ((unsigned)f2bf(src[3 * 128]) << 16);
  o.z = (unsigned)f2bf(src[4 * 128])  | ((unsigned)f2bf(src[5 * 128]) << 16);
  o.w = (unsigned)f2bf(src[6 * 128])  | ((unsigned)f2bf(src[7 * 128]) << 16);
  *(uint4*)(W2t + (size_t)ng * 256 + k) = o;
}

// ---------------- GEMM: C = relu(A @ Bt^T + bias), bf16 in/out, f32 acc ----------------
// A [M][lda] bf16 row-major; Bt [N][ldb] bf16 (N x K row-major); tile 128x128, BK=32.
// gridDim.x = N/128, gridDim.y = M/128, gridDim.z = experts (per-operand expert strides).

__global__ __launch_bounds__(256)
void gemm_bt_kernel(const unsigned short* __restrict__ A, int lda, int aES,
                    const unsigned short* __restrict__ Bt, int ldb, int bES,
                    const float* __restrict__ bias, int biasES,
                    unsigned short* __restrict__ C, int ldc, int cES,
                    int K) {
  __shared__ __align__(16) unsigned short As[128 * 32];
  __shared__ __align__(16) unsigned short Bs[128 * 32];
  const int tid = threadIdx.x;
  const int wv = tid >> 6;
  const int lane = tid & 63;
  const int e = blockIdx.z;
  const int m0 = blockIdx.y << 7;
  const int n0 = blockIdx.x << 7;
  const unsigned short* Ab = A + (size_t)e * aES + (size_t)m0 * lda;
  const unsigned short* Bb = Bt + (size_t)e * bES + (size_t)n0 * ldb;
  const float* biasb = bias + (size_t)e * biasES + n0;
  unsigned short* Cb = C + (size_t)e * cES + (size_t)m0 * ldc + n0;

  const int wm = wv & 1;             // wave m-half (0/1)
  const int wn = wv >> 1;            // wave n-half (0/1)
  const int lr = lane >> 2;          // staging row within 16-row group
  const int kg = lane & 3;           // staging k-group (8 bf16 = 16B)
  const int fr = lane & 15;          // frag non-K index
  const int fk = (lane >> 4) << 3;   // frag k offset (0,8,16,24)

  const unsigned short* ga0 = Ab + (size_t)(wv * 32 + lr) * lda + kg * 8;
  const unsigned short* ga1 = ga0 + (size_t)16 * lda;
  const unsigned short* gb0 = Bb + (size_t)(wv * 32 + lr) * ldb + kg * 8;
  const unsigned short* gb1 = gb0 + (size_t)16 * ldb;
  unsigned short* la0 = &As[(wv * 32) * 32];
  unsigned short* la1 = &As[(wv * 32 + 16) * 32];
  unsigned short* lb0 = &Bs[(wv * 32) * 32];
  unsigned short* lb1 = &Bs[(wv * 32 + 16) * 32];

  floatx4 acc[4][4] = {};

  for (int k0 = 0; k0 < K; k0 += 32) {
    GLDS16(ga0 + k0, la0);
    GLDS16(ga1 + k0, la1);
    GLDS16(gb0 + k0, lb0);
    GLDS16(gb1 + k0, lb1);
    __syncthreads();  // compiler emits vmcnt(0) drain before s_barrier
    short8 af[4], bfg[4];
#pragma unroll
    for (int i = 0; i < 4; i++)
      af[i] = *(const short8*)&As[(wm * 64 + i * 16 + fr) * 32 + fk];
#pragma unroll
    for (int j = 0; j < 4; j++)
      bfg[j] = *(const short8*)&Bs[(wn * 64 + j * 16 + fr) * 32 + fk];
#pragma unroll
    for (int i = 0; i < 4; i++)
#pragma unroll
      for (int j = 0; j < 4; j++)
        acc[i][j] = __builtin_amdgcn_mfma_f32_16x16x32_bf16(af[i], bfg[j], acc[i][j], 0, 0, 0);
    __syncthreads();  // protect LDS before next overwrite
  }

  // epilogue: C/D layout col=lane&15, row=(lane>>4)*4+reg (m89-verified)
  const int rq = (lane >> 4) << 2;
#pragma unroll
  for (int i = 0; i < 4; i++) {
#pragma unroll
    for (int j = 0; j < 4; j++) {
      int cl = wn * 64 + j * 16 + fr;
      float bv = biasb[cl];
#pragma unroll
      for (int r = 0; r < 4; r++) {
        int rw = wm * 64 + i * 16 + rq + r;
        float v = acc[i][j][r] + bv;
        v = v > 0.f ? v : 0.f;
        Cb[(size_t)rw * ldc + cl] = f2bf(v);
      }
    }
  }
}

// ---------------- head: gate (softmax) + expert_out + combine ----------------
// one wave per token; xb global-indexed, h2 chunk-local. f32 outputs.

__global__ __launch_bounds__(256)
void head_kernel(const unsigned short* __restrict__ xb,
                 const unsigned short* __restrict__ h2,
                 const float* __restrict__ Wg, const float* __restrict__ bg,
                 const float* __restrict__ W3, const float* __restrict__ b3,
                 float* __restrict__ outP, float* __restrict__ outG,
                 int base) {
  const int wv = threadIdx.x >> 6, lane = threadIdx.x & 63;
  const int bl = blockIdx.x * 4 + wv;
  const int b = base + bl;
  const unsigned int* xr = (const unsigned int*)xb + (size_t)b * 640;
  const float4* Wg4 = (const float4*)Wg;

  float g[8] = {0.f, 0.f, 0.f, 0.f, 0.f, 0.f, 0.f, 0.f};
  for (int j = lane; j < 640; j += 64) {
    unsigned int u = xr[j];
    float x0 = bf2f(u & 0xffffu);
    float x1 = bf2f(u >> 16);
    float4 wa = Wg4[(size_t)j * 4 + 0];
    float4 wb = Wg4[(size_t)j * 4 + 1];
    float4 wc = Wg4[(size_t)j * 4 + 2];
    float4 wd = Wg4[(size_t)j * 4 + 3];
    g[0] += x0 * wa.x; g[1] += x0 * wa.y; g[2] += x0 * wa.z; g[3] += x0 * wa.w;
    g[4] += x0 * wb.x; g[5] += x0 * wb.y; g[6] += x0 * wb.z; g[7] += x0 * wb.w;
    g[0] += x1 * wc.x; g[1] += x1 * wc.y; g[2] += x1 * wc.z; g[3] += x1 * wc.w;
    g[4] += x1 * wd.x; g[5] += x1 * wd.y; g[6] += x1 * wd.z; g[7] += x1 * wd.w;
  }
#pragma unroll
  for (int e2 = 0; e2 < 8; e2++) {
    float v = g[e2];
    v += __shfl_xor(v, 1);  v += __shfl_xor(v, 2);  v += __shfl_xor(v, 4);
    v += __shfl_xor(v, 8);  v += __shfl_xor(v, 16); v += __shfl_xor(v, 32);
    g[e2] = v + bg[e2];
  }
  float mx = g[0];
#pragma unroll
  for (int e2 = 1; e2 < 8; e2++) mx = fmaxf(mx, g[e2]);
  float se = 0.f;
#pragma unroll
  for (int e2 = 0; e2 < 8; e2++) { g[e2] = __expf(g[e2] - mx); se += g[e2]; }
  float inv = 1.f / se;
#pragma unroll
  for (int e2 = 0; e2 < 8; e2++) g[e2] *= inv;
  if (lane == 0) {
    float4* gout = (float4*)(outG + (size_t)b * 8);
    gout[0] = make_float4(g[0], g[1], g[2], g[3]);
    gout[1] = make_float4(g[4], g[5], g[6], g[7]);
  }

  // expert_out: lane covers 16 of the 1024 h2 elems; 8 lanes per expert
  const int ee = lane >> 3, seg = lane & 7;
  const uint4* h2r = (const uint4*)(h2 + (size_t)bl * 1024) + lane * 2;
  uint4 ua = h2r[0], ub = h2r[1];
  const float4* w3r = (const float4*)(W3 + ee * 128 + seg * 16);
  float4 w0 = w3r[0], w1 = w3r[1], w2 = w3r[2], w3v = w3r[3];
  float s =
      bf2f(ua.x & 0xffffu) * w0.x + bf2f(ua.x >> 16) * w0.y +
      bf2f(ua.y & 0xffffu) * w0.z + bf2f(ua.y >> 16) * w0.w +
      bf2f(ua.z & 0xffffu) * w1.x + bf2f(ua.z >> 16) * w1.y +
      bf2f(ua.w & 0xffffu) * w1.z + bf2f(ua.w >> 16) * w1.w +
      bf2f(ub.x & 0xffffu) * w2.x + bf2f(ub.x >> 16) * w2.y +
      bf2f(ub.y & 0xffffu) * w2.z + bf2f(ub.y >> 16) * w2.w +
      bf2f(ub.z & 0xffffu) * w3v.x + bf2f(ub.z >> 16) * w3v.y +
      bf2f(ub.w & 0xffffu) * w3v.z + bf2f(ub.w >> 16) * w3v.w;
  s += __shfl_xor(s, 1); s += __shfl_xor(s, 2); s += __shfl_xor(s, 4);
  s += b3[ee];
  float pred = 0.f;
#pragma unroll
  for (int e2 = 0; e2 < 8; e2++) pred += g[e2] * __shfl(s, e2 * 8);
  if (lane == 0) outP[b] = pred;
}

// ---------------- launch ----------------

extern "C" void kernel_launch(void* const* d_in, const int* in_sizes, int n_in,
                              void* d_out, int out_size, void* d_ws, size_t ws_size,
                              hipStream_t stream) {
  const float* x  = (const float*)d_in[0];
  const float* W1 = (const float*)d_in[1];
  const float* b1 = (const float*)d_in[2];
  const float* W2 = (const float*)d_in[3];
  const float* b2 = (const float*)d_in[4];
  const float* W3 = (const float*)d_in[5];
  const float* b3 = (const float*)d_in[6];
  const float* Wg = (const float*)d_in[7];
  const float* bg = (const float*)d_in[8];
  float* outP = (float*)d_out;        // predictions [B] f32
  float* outG = outP + NTOK;          // gate [B][8] f32

  char* ws = (char*)d_ws;
  unsigned short* xb  = (unsigned short*)ws;                 // 167,772,160 B
  unsigned short* W1t = (unsigned short*)(ws + 167772160ll); //   5,242,880 B
  unsigned short* W2t = (unsigned short*)(ws + 173015040ll); //     524,288 B
  char* dynbase = ws + 173539328ll;

  // chunk token dim if ws is small: need fixed 173.5MB + Bc*6144 B
  int NC = 1;
  while (NC < 64) {
    size_t need = 173539328ull + (size_t)(NTOK / NC) * 6144ull;
    if (need <= ws_size) break;
    NC <<= 1;
  }
  const int Bc = NTOK / NC;
  unsigned short* h1 = (unsigned short*)dynbase;            // [Bc][2048] bf16
  unsigned short* h2 = h1 + (size_t)Bc * 2048;              // [Bc][1024] bf16

  cast_x_kernel<<<NTOK * KDIM / 4 / 256, 256, 0, stream>>>((const float4*)x, (uint2*)xb);
  pack_w1_kernel<<<(2048 * 160 + 255) / 256, 256, 0, stream>>>(W1, W1t);
  pack_w2_kernel<<<(1024 * 32 + 255) / 256, 256, 0, stream>>>(W2, W2t);

  for (int c = 0; c < NC; c++) {
    int base = c * Bc;
    // layer 1: h1 = relu(xb @ W1 + b1), M=Bc, N=2048, K=1280
    gemm_bt_kernel<<<dim3(16, Bc / 128, 1), 256, 0, stream>>>(
        xb + (size_t)base * 1280, 1280, 0,
        W1t, 1280, 0,
        b1, 0,
        h1, 2048, 0,
        1280);
    // layer 2 (per expert): h2[e] = relu(h1[:, e*256:+256] @ W2[e] + b2[e]), N=128, K=256
    gemm_bt_kernel<<<dim3(1, Bc / 128, 8), 256, 0, stream>>>(
        h1, 2048, 256,
        W2t, 256, 128 * 256,
        b2, 128,
        h2, 1024, 128,
        256);
    head_kernel<<<Bc / 4, 256, 0, stream>>>(xb, h2, Wg, bg, W3, b3, outP, outG, base);
  }
}

// Round 3
// 1098.551 us; speedup vs baseline: 1.1410x; 1.1410x over previous
//
#include <hip/hip_runtime.h>
#include <stdint.h>

#define NTOK 65536
#define KDIM 1280

typedef __attribute__((ext_vector_type(8))) short short8;
typedef __attribute__((ext_vector_type(4))) float floatx4;

__device__ __forceinline__ unsigned short f2bf(float f) {
  union { float f; unsigned int u; } v; v.f = f;
  unsigned int r = v.u + 0x7FFFu + ((v.u >> 16) & 1u);  // RNE
  return (unsigned short)(r >> 16);
}
__device__ __forceinline__ float bf2f(unsigned int u16) {
  union { unsigned int u; float f; } v; v.u = u16 << 16; return v.f;
}

// async global->LDS, 16B per lane; lds base wave-uniform (HW adds lane*16)
#define GLDS16(gp, lp) \
  __builtin_amdgcn_global_load_lds((const __attribute__((address_space(1))) void*)(gp), \
                                   (__attribute__((address_space(3))) void*)(lp), 16, 0, 0)

// ---------------- prep kernels ----------------

__global__ __launch_bounds__(256) void cast_x_kernel(const float4* __restrict__ x,
                                                     uint2* __restrict__ xb) {
  size_t i = (size_t)blockIdx.x * 256 + threadIdx.x;
  float4 v = x[i];
  uint2 o;
  o.x = (unsigned)f2bf(v.x) | ((unsigned)f2bf(v.y) << 16);
  o.y = (unsigned)f2bf(v.z) | ((unsigned)f2bf(v.w) << 16);
  xb[i] = o;
}

// W1 [E][1280][256] f32 -> W1t [n=e*256+h][k] bf16
__global__ __launch_bounds__(256) void pack_w1_kernel(const float* __restrict__ W1,
                                                      unsigned short* __restrict__ W1t) {
  int t = blockIdx.x * 256 + threadIdx.x;
  if (t >= 2048 * 160) return;
  int n = t / 160, kg = t - n * 160;
  int e = n >> 8, h = n & 255;
  int k = kg * 8;
  const float* src = W1 + ((size_t)e * 1280 + k) * 256 + h;
  uint4 o;
  o.x = (unsigned)f2bf(src[0])       | ((unsigned)f2bf(src[256])     << 16);
  o.y = (unsigned)f2bf(src[2 * 256]) | ((unsigned)f2bf(src[3 * 256]) << 16);
  o.z = (unsigned)f2bf(src[4 * 256]) | ((unsigned)f2bf(src[5 * 256]) << 16);
  o.w = (unsigned)f2bf(src[6 * 256]) | ((unsigned)f2bf(src[7 * 256]) << 16);
  *(uint4*)(W1t + (size_t)n * 1280 + k) = o;
}

// W2 [E][256][128] f32 -> W2t [e][n=0..127][k=0..255] bf16
__global__ __launch_bounds__(256) void pack_w2_kernel(const float* __restrict__ W2,
                                                      unsigned short* __restrict__ W2t) {
  int t = blockIdx.x * 256 + threadIdx.x;
  if (t >= 1024 * 32) return;
  int ng = t >> 5, kg = t & 31;
  int e = ng >> 7, n = ng & 127;
  int k = kg * 8;
  const float* src = W2 + (size_t)e * 32768 + (size_t)k * 128 + n;
  uint4 o;
  o.x = (unsigned)f2bf(src[0])       | ((unsigned)f2bf(src[128])     << 16);
  o.y = (unsigned)f2bf(src[2 * 128]) | ((unsigned)f2bf(src[3 * 128]) << 16);
  o.z = (unsigned)f2bf(src[4 * 128]) | ((unsigned)f2bf(src[5 * 128]) << 16);
  o.w = (unsigned)f2bf(src[6 * 128]) | ((unsigned)f2bf(src[7 * 128]) << 16);
  *(uint4*)(W2t + (size_t)ng * 256 + k) = o;
}

// Wg [1280][8] f32 -> WgTb [16][1280] bf16 (rows 8..15 zero-pad)
__global__ __launch_bounds__(256) void pack_wg_kernel(const float* __restrict__ Wg,
                                                      unsigned short* __restrict__ WgTb) {
  int t = blockIdx.x * 256 + threadIdx.x;
  if (t >= 16 * 1280) return;
  int e = t / 1280, k = t - e * 1280;
  WgTb[t] = (e < 8) ? f2bf(Wg[(size_t)k * 8 + e]) : (unsigned short)0;
}

// ---------------- gate: softmax(x@Wg+bg) via MFMA, writes outG (f32) ----------------
// 4 waves/block, 16 tokens/wave. B = WgT padded to 16 "experts" (zeros for 8..15).

__global__ __launch_bounds__(256)
void gate_kernel(const unsigned short* __restrict__ xb,
                 const unsigned short* __restrict__ WgTb,
                 const float* __restrict__ bg,
                 float* __restrict__ outG) {
  __shared__ __align__(16) unsigned short WgL[16][1288];  // +8 pad: 2-way banks
  const int tid = threadIdx.x;
#pragma unroll
  for (int r = 0; r < 16; r++)
    if (tid < 160)
      *(uint4*)&WgL[r][tid * 8] = ((const uint4*)(WgTb + (size_t)r * 1280))[tid];
  __syncthreads();

  const int wv = tid >> 6, lane = tid & 63;
  const int fr = lane & 15;
  const int fkL = (lane >> 4) * 8;
  const int t0 = (blockIdx.x * 4 + wv) * 16;

  const unsigned short* arow = xb + (size_t)(t0 + fr) * 1280 + fkL;
  floatx4 acc = {0.f, 0.f, 0.f, 0.f};
  for (int k0 = 0; k0 < 1280; k0 += 32) {
    short8 af = *(const short8*)(arow + k0);
    short8 bf = *(const short8*)&WgL[fr][k0 + fkL];
    acc = __builtin_amdgcn_mfma_f32_16x16x32_bf16(af, bf, acc, 0, 0, 0);
  }
  // C[m=token=quad*4+r][n=expert=lane&15]
  const int ee = fr;
  float bgv = (ee < 8) ? bg[ee] : 0.f;
#pragma unroll
  for (int r = 0; r < 4; r++) {
    float v = acc[r] + bgv;
    float mx = v;
    mx = fmaxf(mx, __shfl_xor(mx, 1));
    mx = fmaxf(mx, __shfl_xor(mx, 2));
    mx = fmaxf(mx, __shfl_xor(mx, 4));
    float ex = __expf(v - mx);
    float s = ex;
    s += __shfl_xor(s, 1); s += __shfl_xor(s, 2); s += __shfl_xor(s, 4);
    float g = ex / s;
    if (ee < 8) outG[(size_t)(t0 + (lane >> 4) * 4 + r) * 8 + ee] = g;
  }
}

// ---------------- fused expert MLP: relu(relu(x@W1+b1)@W2+b2)@W3 (+b3) ----------------
// grid (8 experts, 1024 token-tiles of 64). 256 thr = 4 waves.
// Phase 1 (A=W1t rows=hidden, B=xb cols=tokens): C rows=hidden k-index -> packed
// ds_write_b64 transpose into h1L[token][k] (stride 264).
// Phase 2 (A=W2t rows=h2, B=h1L): C rows=h2, cols=tokens.
// Phase 3: in-register relu(+b2)*W3 reduction + shuffles -> eo[token][e].

__global__ __launch_bounds__(256)
void expert_fused_kernel(const unsigned short* __restrict__ xb,
                         const unsigned short* __restrict__ W1t,
                         const float* __restrict__ b1,
                         const unsigned short* __restrict__ W2t,
                         const float* __restrict__ b2,
                         const float* __restrict__ W3,
                         const float* __restrict__ b3,
                         float* __restrict__ eo) {
  __shared__ __align__(16) unsigned short Ws[256 * 32];   // 16KB (phase2: first 8KB)
  __shared__ __align__(16) unsigned short Xs[64 * 32];    // 4KB
  __shared__ __align__(16) unsigned short h1L[64 * 264];  // 33KB [token][256+8pad]
  __shared__ float b1Ls[256];
  __shared__ float b2Ls[128];
  __shared__ float w3Ls[128];
  __shared__ float exS[4 * 64];

  const int tid = threadIdx.x;
  const int wv = tid >> 6;
  const int lane = tid & 63;
  const int e = blockIdx.x;
  const int m0 = blockIdx.y << 6;

  const unsigned short* W1te = W1t + (size_t)e * 256 * 1280;
  const unsigned short* W2te = W2t + (size_t)e * 128 * 256;

  b1Ls[tid] = b1[e * 256 + tid];
  if (tid < 128) { b2Ls[tid] = b2[e * 128 + tid]; w3Ls[tid] = W3[e * 128 + tid]; }
  // visibility covered by the first loop barrier

  const int lr = lane >> 2;                                   // staging row-in-16
  const int ksw = ((lane & 3) ^ ((lane >> 3) & 3)) * 8;       // swizzled src k-offset
  const int fr = lane & 15;
  const int fkS = (((lane >> 4) ^ ((lane >> 1) & 3)) & 3) * 8; // swizzled frag slot
  const int fkL = (lane >> 4) * 8;                            // logical frag k-offset
  const int rq = (lane >> 4) * 4;

  const unsigned short* gx = xb + (size_t)(m0 + wv * 16 + lr) * 1280 + ksw;
  const unsigned short* gw = W1te + (size_t)(wv * 64 + lr) * 1280 + ksw;
  unsigned short* lx = &Xs[(wv * 16) * 32];
  unsigned short* lw = &Ws[(wv * 64) * 32];

  // ---- phase 1: h1^T tile (256 hidden x 64 tokens), K=1280 ----
  floatx4 acc1[4][4] = {};
  for (int k0 = 0; k0 < 1280; k0 += 32) {
    GLDS16(gx + k0, lx);
    GLDS16(gw + k0, lw);
    GLDS16(gw + (size_t)16 * 1280 + k0, lw + 16 * 32);
    GLDS16(gw + (size_t)32 * 1280 + k0, lw + 32 * 32);
    GLDS16(gw + (size_t)48 * 1280 + k0, lw + 48 * 32);
    __syncthreads();
    short8 af[4], bfv[4];
#pragma unroll
    for (int i = 0; i < 4; i++)
      af[i] = *(const short8*)&Ws[(wv * 64 + i * 16 + fr) * 32 + fkS];
#pragma unroll
    for (int j = 0; j < 4; j++)
      bfv[j] = *(const short8*)&Xs[(j * 16 + fr) * 32 + fkS];
#pragma unroll
    for (int i = 0; i < 4; i++)
#pragma unroll
      for (int j = 0; j < 4; j++)
        acc1[i][j] = __builtin_amdgcn_mfma_f32_16x16x32_bf16(af[i], bfv[j], acc1[i][j], 0, 0, 0);
    __syncthreads();
  }

  // ---- epilogue 1: relu(+b1), bf16, transpose to h1L[token][k] ----
#pragma unroll
  for (int i = 0; i < 4; i++) {
    const int rowb = wv * 64 + i * 16 + rq;  // hidden k-index base (4 consecutive)
    float bb0 = b1Ls[rowb], bb1 = b1Ls[rowb + 1], bb2 = b1Ls[rowb + 2], bb3 = b1Ls[rowb + 3];
#pragma unroll
    for (int j = 0; j < 4; j++) {
      float v0 = acc1[i][j][0] + bb0; v0 = v0 > 0.f ? v0 : 0.f;
      float v1 = acc1[i][j][1] + bb1; v1 = v1 > 0.f ? v1 : 0.f;
      float v2 = acc1[i][j][2] + bb2; v2 = v2 > 0.f ? v2 : 0.f;
      float v3 = acc1[i][j][3] + bb3; v3 = v3 > 0.f ? v3 : 0.f;
      uint2 pk;
      pk.x = (unsigned)f2bf(v0) | ((unsigned)f2bf(v1) << 16);
      pk.y = (unsigned)f2bf(v2) | ((unsigned)f2bf(v3) << 16);
      *(uint2*)&h1L[(j * 16 + fr) * 264 + rowb] = pk;
    }
  }
  __syncthreads();

  // ---- phase 2: h2 tile (128 h2 x 64 tokens), K=256 ----
  floatx4 acc2[2][4] = {};
  const unsigned short* gw2 = W2te + (size_t)(wv * 32 + lr) * 256 + ksw;
  unsigned short* lw2 = &Ws[(wv * 32) * 32];
  for (int k0 = 0; k0 < 256; k0 += 32) {
    GLDS16(gw2 + k0, lw2);
    GLDS16(gw2 + 16 * 256 + k0, lw2 + 16 * 32);
    __syncthreads();
    short8 a2[2], b2v[4];
#pragma unroll
    for (int i = 0; i < 2; i++)
      a2[i] = *(const short8*)&Ws[(wv * 32 + i * 16 + fr) * 32 + fkS];
#pragma unroll
    for (int j = 0; j < 4; j++)
      b2v[j] = *(const short8*)&h1L[(j * 16 + fr) * 264 + k0 + fkL];
#pragma unroll
    for (int i = 0; i < 2; i++)
#pragma unroll
      for (int j = 0; j < 4; j++)
        acc2[i][j] = __builtin_amdgcn_mfma_f32_16x16x32_bf16(a2[i], b2v[j], acc2[i][j], 0, 0, 0);
    __syncthreads();
  }

  // ---- phase 3: expert_out = relu(h2+b2) . W3 ----
  float psum[4] = {0.f, 0.f, 0.f, 0.f};
#pragma unroll
  for (int i = 0; i < 2; i++) {
    const int rowb = wv * 32 + i * 16 + rq;  // h2 index base
    float bb[4], ww[4];
#pragma unroll
    for (int r = 0; r < 4; r++) { bb[r] = b2Ls[rowb + r]; ww[r] = w3Ls[rowb + r]; }
#pragma unroll
    for (int j = 0; j < 4; j++)
#pragma unroll
      for (int r = 0; r < 4; r++) {
        float v = acc2[i][j][r] + bb[r];
        v = v > 0.f ? v : 0.f;
        psum[j] += v * ww[r];
      }
  }
#pragma unroll
  for (int j = 0; j < 4; j++) {
    float v = psum[j];
    v += __shfl_xor(v, 16);
    v += __shfl_xor(v, 32);
    psum[j] = v;
  }
  if (lane < 16) {
#pragma unroll
    for (int j = 0; j < 4; j++) exS[wv * 64 + j * 16 + lane] = psum[j];
  }
  __syncthreads();
  if (tid < 64) {
    float tot = exS[tid] + exS[64 + tid] + exS[128 + tid] + exS[192 + tid];
    eo[(size_t)(m0 + tid) * 8 + e] = tot + b3[e];
  }
}

// ---------------- combine: predictions = sum(gate * eo) ----------------

__global__ __launch_bounds__(256)
void combine_kernel(const float* __restrict__ outG, const float* __restrict__ eo,
                    float* __restrict__ outP) {
  int t = blockIdx.x * 256 + threadIdx.x;
  const float4* g4 = (const float4*)(outG + (size_t)t * 8);
  const float4* e4 = (const float4*)(eo + (size_t)t * 8);
  float4 ga = g4[0], gb = g4[1], ea = e4[0], eb = e4[1];
  outP[t] = ga.x * ea.x + ga.y * ea.y + ga.z * ea.z + ga.w * ea.w +
            gb.x * eb.x + gb.y * eb.y + gb.z * eb.z + gb.w * eb.w;
}

// ---------------- launch ----------------

extern "C" void kernel_launch(void* const* d_in, const int* in_sizes, int n_in,
                              void* d_out, int out_size, void* d_ws, size_t ws_size,
                              hipStream_t stream) {
  const float* x  = (const float*)d_in[0];
  const float* W1 = (const float*)d_in[1];
  const float* b1 = (const float*)d_in[2];
  const float* W2 = (const float*)d_in[3];
  const float* b2 = (const float*)d_in[4];
  const float* W3 = (const float*)d_in[5];
  const float* b3 = (const float*)d_in[6];
  const float* Wg = (const float*)d_in[7];
  const float* bg = (const float*)d_in[8];
  float* outP = (float*)d_out;   // predictions [B] f32
  float* outG = outP + NTOK;     // gate [B][8] f32

  char* ws = (char*)d_ws;
  unsigned short* xb   = (unsigned short*)ws;                 // 167,772,160
  unsigned short* W1t  = (unsigned short*)(ws + 167772160ll); //   5,242,880
  unsigned short* W2t  = (unsigned short*)(ws + 173015040ll); //     524,288
  unsigned short* WgTb = (unsigned short*)(ws + 173539328ll); //      40,960
  float*          eo   = (float*)(ws + 173580288ll);          //   2,097,152  (tot ~175.7MB)

  cast_x_kernel<<<NTOK * KDIM / 4 / 256, 256, 0, stream>>>((const float4*)x, (uint2*)xb);
  pack_w1_kernel<<<1280, 256, 0, stream>>>(W1, W1t);
  pack_w2_kernel<<<128, 256, 0, stream>>>(W2, W2t);
  pack_wg_kernel<<<80, 256, 0, stream>>>(Wg, WgTb);

  gate_kernel<<<1024, 256, 0, stream>>>(xb, WgTb, bg, outG);
  expert_fused_kernel<<<dim3(8, 1024), 256, 0, stream>>>(xb, W1t, b1, W2t, b2, W3, b3, eo);
  combine_kernel<<<256, 256, 0, stream>>>(outG, eo, outP);
}